// Round 1
// baseline (371.643 us; speedup 1.0000x reference)
//
#include <hip/hip_runtime.h>
#include <hip/hip_bf16.h>

#define NN 8192
#define EE 40960
#define FIN 32
#define HH 64
#define GG 64

typedef __attribute__((ext_vector_type(4))) float f32x4;
typedef __attribute__((ext_vector_type(8))) short s16x8;
typedef unsigned short ushort_t;

__device__ __forceinline__ unsigned short f2bf(float f) {
    union { float f; unsigned int u; } v; v.f = f;
    unsigned int u = v.u;
    return (unsigned short)((u + 0x7fffu + ((u >> 16) & 1u)) >> 16);
}

// ---------------- zero scratch accumulators ----------------
__global__ void zero_kernel(int* __restrict__ cnt, int* __restrict__ fill, float* __restrict__ stats) {
    int i = blockIdx.x * 256 + threadIdx.x;
    if (i < NN) { cnt[i] = 0; fill[i] = 0; }
    if (i < 384) stats[i] = 0.f;
}

// ---------------- Bt build: Bt[o][k*IC+i] = w2[k][i*64+o]; bias rows appended ----------------
template<int IC>
__global__ void btbuild_kernel(const float* __restrict__ w2, const float* __restrict__ b2,
                               ushort_t* __restrict__ Bt) {
    constexpr int KP = 65 * IC;
    int idx = blockIdx.x * 256 + threadIdx.x;
    if (idx >= 64 * KP) return;
    int o = idx / KP, kidx = idx - o * KP;
    float v;
    if (kidx < 64 * IC) {
        int k = kidx / IC, i = kidx & (IC - 1);
        v = w2[k * (IC * 64) + i * 64 + o];
    } else {
        int i = kidx - 64 * IC;
        v = b2[i * 64 + o];
    }
    Bt[(size_t)o * KP + kidx] = f2bf(v);
}

// ---------------- CSR build ----------------
__global__ void hist_kernel(const int* __restrict__ dst, int* __restrict__ cnt) {
    int e = blockIdx.x * 256 + threadIdx.x;
    if (e < EE) atomicAdd(&cnt[dst[e]], 1);
}

__global__ void scan_kernel(const int* __restrict__ cnt, int* __restrict__ row_ptr) {
    __shared__ int lds[1024];
    int t = threadIdx.x;
    int v[8]; int s = 0;
    int base = t * 8;
#pragma unroll
    for (int j = 0; j < 8; j++) { v[j] = s; s += cnt[base + j]; }
    lds[t] = s;
    __syncthreads();
    for (int off = 1; off < 1024; off <<= 1) {
        int add = (t >= off) ? lds[t - off] : 0;
        __syncthreads();
        lds[t] += add;
        __syncthreads();
    }
    int ex = lds[t] - s;
#pragma unroll
    for (int j = 0; j < 8; j++) row_ptr[base + j] = ex + v[j];
    if (t == 1023) row_ptr[NN] = lds[1023];
}

__global__ void scatter_kernel(const int* __restrict__ dst, const int* __restrict__ row_ptr,
                               int* __restrict__ fill, int* __restrict__ perm) {
    int e = blockIdx.x * 256 + threadIdx.x;
    if (e < EE) {
        int d = dst[e];
        int pos = row_ptr[d] + atomicAdd(&fill[d], 1);
        perm[pos] = e;
    }
}

// ---------------- edge MLP first layer: h = relu(ea @ w1 + b1) ----------------
__global__ void h_kernel(const float* __restrict__ ea, const float* __restrict__ w1,
                         const float* __restrict__ b1, float* __restrict__ h) {
    __shared__ float w1s[512];
    __shared__ float b1s[64];
    int t = threadIdx.x;
    for (int i = t; i < 512; i += 256) w1s[i] = w1[i];
    if (t < 64) b1s[t] = b1[t];
    __syncthreads();
    int idx = blockIdx.x * 256 + t;
    int e = idx >> 6, j = idx & 63;
    const float* ar = ea + (size_t)e * 8;
    float s = b1s[j];
#pragma unroll
    for (int i = 0; i < 8; i++) s += ar[i] * w1s[i * 64 + j];
    h[idx] = fmaxf(s, 0.f);
}

// ---------------- fused NNConv message GEMM (MFMA, bf16 operands, fp32 accum) ----------------
// msg[e,o] = sum_k h[e,k] * (xs[e,:] @ Bk[:,o])  + bias-step (h == 1)
template<int IC>
__launch_bounds__(256)
__global__ void conv_msg_kernel(const float* __restrict__ hbuf,
                                const float* __restrict__ xin,
                                const int* __restrict__ src,
                                const ushort_t* __restrict__ Bt,
                                float* __restrict__ msg) {
    constexpr int KP  = 65 * IC;
    constexpr int CH  = IC / 8;          // 16B chunks per Bt row per step
    constexpr int NKK = IC / 32;         // MFMA K=32 slabs per step
    constexpr int CPT = (64 * CH) / 256; // chunks staged per thread
    __shared__ ushort_t bt_lds[64 * IC];
    __shared__ float h_t[4096];          // h transposed [k][e], XOR-swizzled by k&28

    const int t = threadIdx.x;
    const int wave = t >> 6;
    const int l = t & 63;
    const int g = l >> 4;
    const int rlo = l & 15;
    const int e0 = blockIdx.x * 64;

    // stage h transposed (coalesced global reads)
    for (int idx = t; idx < 4096; idx += 256) {
        int e = idx >> 6, k = idx & 63;
        h_t[(k << 6) + (e ^ (k & 28))] = hbuf[(size_t)(e0 + e) * 64 + k];
    }

    // hoisted A fragments: afrag[m][kk] = bf16(xs[row, kk*32 + g*8 .. +8])
    s16x8 afrag[4][NKK];
#pragma unroll
    for (int m = 0; m < 4; ++m) {
        int row = m * 16 + rlo;
        int sn = src[e0 + row];
        const float* xp = xin + (size_t)sn * IC + g * 8;
#pragma unroll
        for (int kk = 0; kk < NKK; ++kk) {
            f32x4 a = *(const f32x4*)(xp + kk * 32);
            f32x4 b = *(const f32x4*)(xp + kk * 32 + 4);
            s16x8 fr;
            fr[0] = (short)f2bf(a[0]); fr[1] = (short)f2bf(a[1]);
            fr[2] = (short)f2bf(a[2]); fr[3] = (short)f2bf(a[3]);
            fr[4] = (short)f2bf(b[0]); fr[5] = (short)f2bf(b[1]);
            fr[6] = (short)f2bf(b[2]); fr[7] = (short)f2bf(b[3]);
            afrag[m][kk] = fr;
        }
    }

    f32x4 acc[4];
#pragma unroll
    for (int m = 0; m < 4; m++) acc[m] = (f32x4){0.f, 0.f, 0.f, 0.f};

    const int scol = t >> 2, sq = t & 3;
    const ushort_t* btrow = Bt + (size_t)scol * KP;
    f32x4 breg[CPT];
    const int bcol = wave * 16 + rlo;

    auto stage_load = [&](int step) {
        const ushort_t* p = btrow + step * IC + sq * (CPT * 8);
#pragma unroll
        for (int c = 0; c < CPT; c++) breg[c] = *(const f32x4*)(p + c * 8);
    };
    auto stage_write = [&]() {
#pragma unroll
        for (int c = 0; c < CPT; c++) {
            int ch = sq * CPT + c;
            int sw = ch ^ (scol & (CH - 1));
            *(f32x4*)&bt_lds[scol * IC + sw * 8] = breg[c];
        }
    };

    stage_load(0);
    stage_write();
    __syncthreads();

    for (int step = 0; step < 65; ++step) {
        if (step < 64) stage_load(step + 1);   // prefetch next B tile to regs
        s16x8 bfrag[NKK];
#pragma unroll
        for (int kk = 0; kk < NKK; kk++) {
            int ch = kk * 4 + g;
            int sw = ch ^ (bcol & (CH - 1));
            bfrag[kk] = *(const s16x8*)&bt_lds[bcol * IC + sw * 8];
        }
        const f32x4 zf = (f32x4){0.f, 0.f, 0.f, 0.f};
#pragma unroll
        for (int m = 0; m < 4; m++) {
            f32x4 P = __builtin_amdgcn_mfma_f32_16x16x32_bf16(afrag[m][0], bfrag[0], zf, 0, 0, 0);
            if constexpr (NKK == 2)
                P = __builtin_amdgcn_mfma_f32_16x16x32_bf16(afrag[m][1], bfrag[1], P, 0, 0, 0);
            if (step == 64) {
                acc[m] += P;                    // bias step: h == 1
            } else {
                f32x4 h4 = *(const f32x4*)&h_t[(step << 6) + ((m * 16 + (g << 2)) ^ (step & 28))];
                acc[m] += h4 * P;
            }
        }
        if (step < 64) { __syncthreads(); stage_write(); __syncthreads(); }
    }

    // C/D layout: row = g*4 + r (+m*16), col = wave*16 + (l&15)
#pragma unroll
    for (int m = 0; m < 4; m++) {
        int row = e0 + m * 16 + (g << 2);
        float* mp = msg + (size_t)row * 64 + wave * 16 + rlo;
        mp[0] = acc[m][0]; mp[64] = acc[m][1]; mp[128] = acc[m][2]; mp[192] = acc[m][3];
    }
}

// ---------------- aggregate: y = seg_mean(msg) + x@root_w + root_b; fused BN stats ----------------
__global__ void aggregate_kernel(const float* __restrict__ msg, const int* __restrict__ row_ptr,
                                 const int* __restrict__ perm, const float* __restrict__ xin, int IC,
                                 const float* __restrict__ root_w, const float* __restrict__ root_b,
                                 float* __restrict__ y, float* __restrict__ stats) {
    int t = threadIdx.x;
    int n = blockIdx.x * 16 + (t >> 4);
    int cg = (t & 15) * 4;
    int s = row_ptr[n], e = row_ptr[n + 1];
    f32x4 acc = (f32x4){0.f, 0.f, 0.f, 0.f};
    for (int j = s; j < e; ++j) {
        int ed = perm[j];
        acc += *(const f32x4*)&msg[(size_t)ed * 64 + cg];
    }
    float inv = 1.0f / fmaxf((float)(e - s), 1.0f);
    acc *= inv;
    const float* xr = xin + (size_t)n * IC;
    for (int i = 0; i < IC; ++i) {
        float xv = xr[i];
        acc += xv * (*(const f32x4*)&root_w[i * 64 + cg]);
    }
    acc += *(const f32x4*)&root_b[cg];
    *(f32x4*)&y[(size_t)n * 64 + cg] = acc;

    // BN stats: reduce over the wave's 4 nodes, then across 4 waves in LDS, one atomic per col
    f32x4 a2 = acc * acc;
#pragma unroll
    for (int j = 0; j < 4; j++) {
        acc[j] += __shfl_xor(acc[j], 16); acc[j] += __shfl_xor(acc[j], 32);
        a2[j]  += __shfl_xor(a2[j], 16);  a2[j]  += __shfl_xor(a2[j], 32);
    }
    __shared__ float ls[4][64], lq[4][64];
    int w = t >> 6;
    if ((t & 63) < 16) {
#pragma unroll
        for (int j = 0; j < 4; j++) { ls[w][cg + j] = acc[j]; lq[w][cg + j] = a2[j]; }
    }
    __syncthreads();
    if (t < 64) {
        float S = ls[0][t] + ls[1][t] + ls[2][t] + ls[3][t];
        float Q = lq[0][t] + lq[1][t] + lq[2][t] + lq[3][t];
        atomicAdd(&stats[t], S);
        atomicAdd(&stats[64 + t], Q);
    }
}

// ---------------- BN apply + relu (+ residual) ----------------
__global__ void bn_apply_kernel(const float* __restrict__ y, const float* __restrict__ stats,
                                const float* __restrict__ gam, const float* __restrict__ bet,
                                const float* __restrict__ res, float* __restrict__ xout) {
    int idx = blockIdx.x * 256 + threadIdx.x;
    int c = idx & 63;
    const float invN = 1.0f / (float)NN;
    float mean = stats[c] * invN;
    float var = stats[64 + c] * invN - mean * mean;
    float sc = rsqrtf(var + 1e-5f) * gam[c];
    float v = (y[idx] - mean) * sc + bet[c];
    v = fmaxf(v, 0.f);
    if (res) v += res[idx];
    xout[idx] = v;
}

// ---------------- attention gate: gate = relu(x3@gw1+gb1)@gw2 + gb2 ----------------
__global__ void gate_kernel(const float* __restrict__ x3, const float* __restrict__ gw1,
                            const float* __restrict__ gb1, const float* __restrict__ gw2,
                            const float* __restrict__ gb2, float* __restrict__ gate) {
    __shared__ float w1s[2048];
    __shared__ float b1s[32];
    __shared__ float w2s[32];
    __shared__ float b2s;
    int t = threadIdx.x;
    for (int i = t; i < 2048; i += 256) w1s[i] = gw1[i];
    if (t < 32) { b1s[t] = gb1[t]; w2s[t] = gw2[t]; }
    if (t == 0) b2s = gb2[0];
    __syncthreads();
    int n = blockIdx.x * 256 + t;
    float hacc[32];
#pragma unroll
    for (int j = 0; j < 32; j++) hacc[j] = b1s[j];
    const float* xr = x3 + (size_t)n * 64;
    for (int i = 0; i < 64; i++) {
        float xv = xr[i];
#pragma unroll
        for (int j = 0; j < 32; j++) hacc[j] += xv * w1s[i * 32 + j];
    }
    float gv = b2s;
#pragma unroll
    for (int j = 0; j < 32; j++) gv += fmaxf(hacc[j], 0.f) * w2s[j];
    gate[n] = gv;
}

// ---------------- per-group softmax-weighted pool ----------------
__global__ void attn_pool_kernel(const float* __restrict__ x3, const float* __restrict__ gate,
                                 const int* __restrict__ batch, float* __restrict__ p) {
    int g = blockIdx.x;
    int t = threadIdx.x;
    int lo = 0, hi = NN;
    while (lo < hi) { int mid = (lo + hi) >> 1; if (batch[mid] < g) lo = mid + 1; else hi = mid; }
    int s = lo;
    hi = NN;
    while (lo < hi) { int mid = (lo + hi) >> 1; if (batch[mid] < g + 1) lo = mid + 1; else hi = mid; }
    int e = lo;

    __shared__ float red[4];
    __shared__ float sM, sZ;
    float m = -1e30f;
    for (int n = s + t; n < e; n += 256) m = fmaxf(m, gate[n]);
#pragma unroll
    for (int off = 1; off < 64; off <<= 1) m = fmaxf(m, __shfl_xor(m, off));
    if ((t & 63) == 0) red[t >> 6] = m;
    __syncthreads();
    if (t == 0) sM = fmaxf(fmaxf(red[0], red[1]), fmaxf(red[2], red[3]));
    __syncthreads();
    float z = 0.f;
    for (int n = s + t; n < e; n += 256) z += __expf(gate[n] - sM);
#pragma unroll
    for (int off = 1; off < 64; off <<= 1) z += __shfl_xor(z, off);
    if ((t & 63) == 0) red[t >> 6] = z;
    __syncthreads();
    if (t == 0) sZ = red[0] + red[1] + red[2] + red[3];
    __syncthreads();
    int w = t >> 6, c = t & 63;
    float acc = 0.f;
    for (int n = s + w; n < e; n += 4) acc += __expf(gate[n] - sM) * x3[(size_t)n * 64 + c];
    __shared__ float pa[4][64];
    pa[w][c] = acc;
    __syncthreads();
    if (t < 64) {
        float v = pa[0][t] + pa[1][t] + pa[2][t] + pa[3][t];
        p[g * 64 + t] = (sZ > 0.f) ? v / sZ : 0.f;
    }
}

// ---------------- final MLP head (single block) ----------------
__global__ void final_kernel(const float* __restrict__ p,
                             const float* __restrict__ fc1w, const float* __restrict__ fc1b,
                             const float* __restrict__ bn1g, const float* __restrict__ bn1b,
                             const float* __restrict__ fc2w, const float* __restrict__ fc2b,
                             const float* __restrict__ bn2g, const float* __restrict__ bn2b,
                             const float* __restrict__ fc3w, const float* __restrict__ fc3b,
                             float* __restrict__ out) {
    __shared__ float sp[4096];   // p, later reused as t2
    __shared__ float t1[8192];
    __shared__ float sA[128], sB[128];
    int t = threadIdx.x;
    for (int i = t; i < 4096; i += 256) sp[i] = p[i];
    __syncthreads();
    for (int idx = t; idx < 8192; idx += 256) {
        int r = idx >> 7, c = idx & 127;
        float s = fc1b[c];
        for (int i = 0; i < 64; i++) s += sp[r * 64 + i] * fc1w[i * 128 + c];
        t1[idx] = s;
    }
    __syncthreads();
    if (t < 128) {
        float su = 0.f, sq = 0.f;
        for (int r = 0; r < 64; r++) { float v = t1[r * 128 + t]; su += v; sq += v * v; }
        float mean = su * (1.f / 64.f);
        float var = sq * (1.f / 64.f) - mean * mean;
        float sc = rsqrtf(var + 1e-5f) * bn1g[t];
        sA[t] = sc; sB[t] = bn1b[t] - mean * sc;
    }
    __syncthreads();
    for (int idx = t; idx < 8192; idx += 256) {
        int c = idx & 127;
        t1[idx] = fmaxf(t1[idx] * sA[c] + sB[c], 0.f);
    }
    __syncthreads();
    for (int idx = t; idx < 4096; idx += 256) {
        int r = idx >> 6, c = idx & 63;
        float s = fc2b[c];
        for (int i = 0; i < 128; i++) s += t1[r * 128 + i] * fc2w[i * 64 + c];
        sp[idx] = s;
    }
    __syncthreads();
    if (t < 64) {
        float su = 0.f, sq = 0.f;
        for (int r = 0; r < 64; r++) { float v = sp[r * 64 + t]; su += v; sq += v * v; }
        float mean = su * (1.f / 64.f);
        float var = sq * (1.f / 64.f) - mean * mean;
        float sc = rsqrtf(var + 1e-5f) * bn2g[t];
        sA[t] = sc; sB[t] = bn2b[t] - mean * sc;
    }
    __syncthreads();
    if (t < 64) {
        float s = fc3b[0];
        for (int ii = 0; ii < 64; ++ii) {
            int i = (ii + t) & 63;  // rotate to avoid LDS bank conflict
            float v = fmaxf(sp[t * 64 + i] * sA[i] + sB[i], 0.f);
            s += v * fc3w[i];
        }
        out[t] = s;
    }
}

extern "C" void kernel_launch(void* const* d_in, const int* in_sizes, int n_in,
                              void* d_out, int out_size, void* d_ws, size_t ws_size,
                              hipStream_t stream) {
    const float* x     = (const float*)d_in[0];
    const int*   eidx  = (const int*)d_in[1];
    const float* eattr = (const float*)d_in[2];
    const int*   batch = (const int*)d_in[3];
    const float* e1w1 = (const float*)d_in[4];  const float* e1b1 = (const float*)d_in[5];
    const float* e1w2 = (const float*)d_in[6];  const float* e1b2 = (const float*)d_in[7];
    const float* r1w  = (const float*)d_in[8];  const float* r1b  = (const float*)d_in[9];
    const float* bn1g = (const float*)d_in[10]; const float* bn1b = (const float*)d_in[11];
    const float* e2w1 = (const float*)d_in[12]; const float* e2b1 = (const float*)d_in[13];
    const float* e2w2 = (const float*)d_in[14]; const float* e2b2 = (const float*)d_in[15];
    const float* r2w  = (const float*)d_in[16]; const float* r2b  = (const float*)d_in[17];
    const float* bn2g = (const float*)d_in[18]; const float* bn2b = (const float*)d_in[19];
    const float* e3w1 = (const float*)d_in[20]; const float* e3b1 = (const float*)d_in[21];
    const float* e3w2 = (const float*)d_in[22]; const float* e3b2 = (const float*)d_in[23];
    const float* r3w  = (const float*)d_in[24]; const float* r3b  = (const float*)d_in[25];
    const float* bn3g = (const float*)d_in[26]; const float* bn3b = (const float*)d_in[27];
    const float* gw1  = (const float*)d_in[28]; const float* gb1  = (const float*)d_in[29];
    const float* gw2  = (const float*)d_in[30]; const float* gb2  = (const float*)d_in[31];
    const float* fc1w = (const float*)d_in[32]; const float* fc1b = (const float*)d_in[33];
    const float* fbn1g= (const float*)d_in[34]; const float* fbn1b= (const float*)d_in[35];
    const float* fc2w = (const float*)d_in[36]; const float* fc2b = (const float*)d_in[37];
    const float* fbn2g= (const float*)d_in[38]; const float* fbn2b= (const float*)d_in[39];
    const float* fc3w = (const float*)d_in[40]; const float* fc3b = (const float*)d_in[41];
    float* out = (float*)d_out;

    const int* src = eidx;
    const int* dst = eidx + EE;

    char* ws = (char*)d_ws;
    size_t off = 0;
    auto take = [&](size_t n) { void* p = ws + off; off = (off + n + 255) & ~(size_t)255; return p; };
    ushort_t* Bt1 = (ushort_t*)take(64 * 2080 * 2);
    ushort_t* Bt2 = (ushort_t*)take(64 * 4160 * 2);
    ushort_t* Bt3 = (ushort_t*)take(64 * 4160 * 2);
    float* hbuf = (float*)take((size_t)EE * 64 * 4);
    float* msg  = (float*)take((size_t)EE * 64 * 4);
    float* ybuf = (float*)take((size_t)NN * 64 * 4);
    float* x1   = (float*)take((size_t)NN * 64 * 4);
    float* x2   = (float*)take((size_t)NN * 64 * 4);
    float* x3   = (float*)take((size_t)NN * 64 * 4);
    float* gate = (float*)take((size_t)NN * 4);
    float* pbuf = (float*)take(64 * 64 * 4);
    float* stats = (float*)take(384 * 4);
    int* cnt  = (int*)take((size_t)NN * 4);
    int* fill = (int*)take((size_t)NN * 4);
    int* rowp = (int*)take((size_t)(NN + 1) * 4);
    int* perm = (int*)take((size_t)EE * 4);

    zero_kernel<<<32, 256, 0, stream>>>(cnt, fill, stats);
    btbuild_kernel<32><<<520, 256, 0, stream>>>(e1w2, e1b2, Bt1);
    btbuild_kernel<64><<<1040, 256, 0, stream>>>(e2w2, e2b2, Bt2);
    btbuild_kernel<64><<<1040, 256, 0, stream>>>(e3w2, e3b2, Bt3);
    hist_kernel<<<160, 256, 0, stream>>>(dst, cnt);
    scan_kernel<<<1, 1024, 0, stream>>>(cnt, rowp);
    scatter_kernel<<<160, 256, 0, stream>>>(dst, rowp, fill, perm);

    // layer 1 (IC = 32)
    h_kernel<<<10240, 256, 0, stream>>>(eattr, e1w1, e1b1, hbuf);
    conv_msg_kernel<32><<<640, 256, 0, stream>>>(hbuf, x, src, Bt1, msg);
    aggregate_kernel<<<512, 256, 0, stream>>>(msg, rowp, perm, x, 32, r1w, r1b, ybuf, stats);
    bn_apply_kernel<<<2048, 256, 0, stream>>>(ybuf, stats, bn1g, bn1b, nullptr, x1);

    // layer 2 (IC = 64)
    h_kernel<<<10240, 256, 0, stream>>>(eattr, e2w1, e2b1, hbuf);
    conv_msg_kernel<64><<<640, 256, 0, stream>>>(hbuf, x1, src, Bt2, msg);
    aggregate_kernel<<<512, 256, 0, stream>>>(msg, rowp, perm, x1, 64, r2w, r2b, ybuf, stats + 128);
    bn_apply_kernel<<<2048, 256, 0, stream>>>(ybuf, stats + 128, bn2g, bn2b, x1, x2);

    // layer 3 (IC = 64)
    h_kernel<<<10240, 256, 0, stream>>>(eattr, e3w1, e3b1, hbuf);
    conv_msg_kernel<64><<<640, 256, 0, stream>>>(hbuf, x2, src, Bt3, msg);
    aggregate_kernel<<<512, 256, 0, stream>>>(msg, rowp, perm, x2, 64, r3w, r3b, ybuf, stats + 256);
    bn_apply_kernel<<<2048, 256, 0, stream>>>(ybuf, stats + 256, bn3g, bn3b, x2, x3);

    gate_kernel<<<32, 256, 0, stream>>>(x3, gw1, gb1, gw2, gb2, gate);
    attn_pool_kernel<<<64, 256, 0, stream>>>(x3, gate, batch, pbuf);
    final_kernel<<<1, 256, 0, stream>>>(pbuf, fc1w, fc1b, fbn1g, fbn1b,
                                        fc2w, fc2b, fbn2g, fbn2b, fc3w, fc3b, out);
}

// Round 2
// 291.402 us; speedup vs baseline: 1.2754x; 1.2754x over previous
//
#include <hip/hip_runtime.h>
#include <hip/hip_bf16.h>

#define NN 8192
#define EE 40960
#define FIN 32
#define HH 64
#define GG 64

typedef __attribute__((ext_vector_type(4))) float f32x4;
typedef __attribute__((ext_vector_type(8))) short s16x8;
typedef unsigned short ushort_t;

__device__ __forceinline__ unsigned short f2bf(float f) {
    union { float f; unsigned int u; } v; v.f = f;
    unsigned int u = v.u;
    return (unsigned short)((u + 0x7fffu + ((u >> 16) & 1u)) >> 16);
}

// ---------------- zero scratch accumulators ----------------
__global__ void zero_kernel(int* __restrict__ cnt, int* __restrict__ fill, float* __restrict__ stats) {
    int i = blockIdx.x * 256 + threadIdx.x;
    if (i < NN) { cnt[i] = 0; fill[i] = 0; }
    if (i < 384) stats[i] = 0.f;
}

// ---------------- Bt build: Bt[o][k*IC+i] = w2[k][i*64+o]; bias rows appended ----------------
template<int IC>
__global__ void btbuild_kernel(const float* __restrict__ w2, const float* __restrict__ b2,
                               ushort_t* __restrict__ Bt) {
    constexpr int KP = 65 * IC;
    int idx = blockIdx.x * 256 + threadIdx.x;
    if (idx >= 64 * KP) return;
    int o = idx / KP, kidx = idx - o * KP;
    float v;
    if (kidx < 64 * IC) {
        int k = kidx / IC, i = kidx & (IC - 1);
        v = w2[k * (IC * 64) + i * 64 + o];
    } else {
        int i = kidx - 64 * IC;
        v = b2[i * 64 + o];
    }
    Bt[(size_t)o * KP + kidx] = f2bf(v);
}

// ---------------- CSR build ----------------
__global__ void hist_kernel(const int* __restrict__ dst, int* __restrict__ cnt) {
    int e = blockIdx.x * 256 + threadIdx.x;
    if (e < EE) atomicAdd(&cnt[dst[e]], 1);
}

__global__ void scan_kernel(const int* __restrict__ cnt, int* __restrict__ row_ptr) {
    __shared__ int lds[1024];
    int t = threadIdx.x;
    int v[8]; int s = 0;
    int base = t * 8;
#pragma unroll
    for (int j = 0; j < 8; j++) { v[j] = s; s += cnt[base + j]; }
    lds[t] = s;
    __syncthreads();
    for (int off = 1; off < 1024; off <<= 1) {
        int add = (t >= off) ? lds[t - off] : 0;
        __syncthreads();
        lds[t] += add;
        __syncthreads();
    }
    int ex = lds[t] - s;
#pragma unroll
    for (int j = 0; j < 8; j++) row_ptr[base + j] = ex + v[j];
    if (t == 1023) row_ptr[NN] = lds[1023];
}

__global__ void scatter_kernel(const int* __restrict__ dst, const int* __restrict__ row_ptr,
                               int* __restrict__ fill, int* __restrict__ perm) {
    int e = blockIdx.x * 256 + threadIdx.x;
    if (e < EE) {
        int d = dst[e];
        int pos = row_ptr[d] + atomicAdd(&fill[d], 1);
        perm[pos] = e;
    }
}

// ---------------- fused NNConv message GEMM (h computed in-block, dst-sorted output) ----------
// msg[sorted e, o] = sum_k h[e,k] * (x[src(e),:] @ Bk[:,o])  + bias-step (h == 1)
template<int IC>
__launch_bounds__(256)
__global__ void conv_msg_kernel(const float* __restrict__ eattr,
                                const float* __restrict__ w1,
                                const float* __restrict__ b1,
                                const float* __restrict__ xin,
                                const int* __restrict__ src,
                                const int* __restrict__ perm,
                                const ushort_t* __restrict__ Bt,
                                float* __restrict__ msg) {
    constexpr int KP  = 65 * IC;
    constexpr int CH  = IC / 8;          // 16B chunks per Bt row per step
    constexpr int NKK = IC / 32;         // MFMA K=32 slabs per step
    constexpr int CPT = (64 * CH) / 256; // chunks staged per thread
    __shared__ ushort_t bt_lds[2][64 * IC];
    __shared__ float h_t[4096];          // h transposed [k][e]
    __shared__ float ea_s[64][9];        // padded: conflict-free stride 9
    __shared__ float w1s[8 * 64];
    __shared__ float b1s[64];
    __shared__ int eid_s[64];

    const int t = threadIdx.x;
    const int wave = t >> 6;
    const int l = t & 63;
    const int g = l >> 4;
    const int rlo = l & 15;
    const int e0 = blockIdx.x * 64;

    // stage sorted edge ids + edge-MLP-1 weights
    if (t < 64) { eid_s[t] = perm[e0 + t]; b1s[t] = b1[t]; }
    for (int i = t; i < 512; i += 256) w1s[i] = w1[i];
    __syncthreads();

    // gather edge_attr rows for this block's (sorted) edges
#pragma unroll
    for (int j = 0; j < 2; j++) {
        int idx = t + 256 * j;
        int e = idx >> 3, i = idx & 7;
        ea_s[e][i] = eattr[(size_t)eid_s[e] * 8 + i];
    }

    // hoisted A fragments: afrag[m][kk] = bf16(x[src, kk*32 + g*8 .. +8])
    s16x8 afrag[4][NKK];
#pragma unroll
    for (int m = 0; m < 4; ++m) {
        int row = m * 16 + rlo;
        int sn = src[eid_s[row]];
        const float* xp = xin + (size_t)sn * IC + g * 8;
#pragma unroll
        for (int kk = 0; kk < NKK; ++kk) {
            f32x4 a = *(const f32x4*)(xp + kk * 32);
            f32x4 b = *(const f32x4*)(xp + kk * 32 + 4);
            s16x8 fr;
            fr[0] = (short)f2bf(a[0]); fr[1] = (short)f2bf(a[1]);
            fr[2] = (short)f2bf(a[2]); fr[3] = (short)f2bf(a[3]);
            fr[4] = (short)f2bf(b[0]); fr[5] = (short)f2bf(b[1]);
            fr[6] = (short)f2bf(b[2]); fr[7] = (short)f2bf(b[3]);
            afrag[m][kk] = fr;
        }
    }

    const int scol = t >> 2, sq = t & 3;
    const ushort_t* btrow = Bt + (size_t)scol * KP;
    f32x4 breg[CPT];
    const int bcol = wave * 16 + rlo;

    auto stage_load = [&](int step) {
        const ushort_t* p = btrow + step * IC + sq * (CPT * 8);
#pragma unroll
        for (int c = 0; c < CPT; c++) breg[c] = *(const f32x4*)(p + c * 8);
    };
    auto stage_write = [&](int buf) {
#pragma unroll
        for (int c = 0; c < CPT; c++) {
            int ch = sq * CPT + c;
            int sw = ch ^ (scol & (CH - 1));
            *(f32x4*)&bt_lds[buf][scol * IC + sw * 8] = breg[c];
        }
    };

    stage_load(0);
    __syncthreads();   // ea_s ready

    // compute h_t[k][e] = relu(b1[k] + ea[e]·w1[:,k])
#pragma unroll
    for (int j = 0; j < 16; ++j) {
        int k = wave * 16 + j;
        int e = l;
        float s = b1s[k];
#pragma unroll
        for (int i = 0; i < 8; i++) s += ea_s[e][i] * w1s[i * 64 + k];
        h_t[(k << 6) + e] = fmaxf(s, 0.f);
    }
    stage_write(0);
    __syncthreads();   // h_t + bt_lds[0] ready

    f32x4 acc[4];
#pragma unroll
    for (int m = 0; m < 4; m++) acc[m] = (f32x4){0.f, 0.f, 0.f, 0.f};

    for (int step = 0; step < 65; ++step) {
        if (step < 64) stage_load(step + 1);   // prefetch next B tile to regs
        const int buf = step & 1;
        s16x8 bfrag[NKK];
#pragma unroll
        for (int kk = 0; kk < NKK; kk++) {
            int ch = kk * 4 + g;
            int sw = ch ^ (bcol & (CH - 1));
            bfrag[kk] = *(const s16x8*)&bt_lds[buf][bcol * IC + sw * 8];
        }
        const f32x4 zf = (f32x4){0.f, 0.f, 0.f, 0.f};
#pragma unroll
        for (int m = 0; m < 4; m++) {
            f32x4 P = __builtin_amdgcn_mfma_f32_16x16x32_bf16(afrag[m][0], bfrag[0], zf, 0, 0, 0);
            if constexpr (NKK == 2)
                P = __builtin_amdgcn_mfma_f32_16x16x32_bf16(afrag[m][1], bfrag[1], P, 0, 0, 0);
            if (step == 64) {
                acc[m] += P;                    // bias step: h == 1
            } else {
                f32x4 h4 = *(const f32x4*)&h_t[(step << 6) + m * 16 + (g << 2)];
                acc[m] += h4 * P;
            }
        }
        if (step < 64) { stage_write(buf ^ 1); __syncthreads(); }
    }

    // C/D layout: row = g*4 + r (+m*16), col = wave*16 + (l&15); rows are sorted positions
#pragma unroll
    for (int m = 0; m < 4; m++) {
        int row = e0 + m * 16 + (g << 2);
        float* mp = msg + (size_t)row * 64 + wave * 16 + rlo;
        mp[0] = acc[m][0]; mp[64] = acc[m][1]; mp[128] = acc[m][2]; mp[192] = acc[m][3];
    }
}

// ---------------- aggregate: y = seg_mean(msg) + x@root_w + root_b; fused BN stats ----------------
__global__ void aggregate_kernel(const float* __restrict__ msg, const int* __restrict__ row_ptr,
                                 const float* __restrict__ xin, int IC,
                                 const float* __restrict__ root_w, const float* __restrict__ root_b,
                                 float* __restrict__ y, float* __restrict__ stats) {
    int t = threadIdx.x;
    int n = blockIdx.x * 16 + (t >> 4);
    int cg = (t & 15) * 4;
    int s = row_ptr[n], e = row_ptr[n + 1];
    f32x4 acc = (f32x4){0.f, 0.f, 0.f, 0.f};
    for (int j = s; j < e; ++j) {
        acc += *(const f32x4*)&msg[(size_t)j * 64 + cg];   // contiguous (dst-sorted)
    }
    float inv = 1.0f / fmaxf((float)(e - s), 1.0f);
    acc *= inv;
    const float* xr = xin + (size_t)n * IC;
    for (int i = 0; i < IC; ++i) {
        float xv = xr[i];
        acc += xv * (*(const f32x4*)&root_w[i * 64 + cg]);
    }
    acc += *(const f32x4*)&root_b[cg];
    *(f32x4*)&y[(size_t)n * 64 + cg] = acc;

    // BN stats: reduce over the wave's 4 nodes, then across 4 waves in LDS, one atomic per col
    f32x4 a2 = acc * acc;
#pragma unroll
    for (int j = 0; j < 4; j++) {
        acc[j] += __shfl_xor(acc[j], 16); acc[j] += __shfl_xor(acc[j], 32);
        a2[j]  += __shfl_xor(a2[j], 16);  a2[j]  += __shfl_xor(a2[j], 32);
    }
    __shared__ float ls[4][64], lq[4][64];
    int w = t >> 6;
    if ((t & 63) < 16) {
#pragma unroll
        for (int j = 0; j < 4; j++) { ls[w][cg + j] = acc[j]; lq[w][cg + j] = a2[j]; }
    }
    __syncthreads();
    if (t < 64) {
        float S = ls[0][t] + ls[1][t] + ls[2][t] + ls[3][t];
        float Q = lq[0][t] + lq[1][t] + lq[2][t] + lq[3][t];
        atomicAdd(&stats[t], S);
        atomicAdd(&stats[64 + t], Q);
    }
}

// ---------------- BN apply + relu (+ residual) ----------------
__global__ void bn_apply_kernel(const float* __restrict__ y, const float* __restrict__ stats,
                                const float* __restrict__ gam, const float* __restrict__ bet,
                                const float* __restrict__ res, float* __restrict__ xout) {
    int idx = blockIdx.x * 256 + threadIdx.x;
    int c = idx & 63;
    const float invN = 1.0f / (float)NN;
    float mean = stats[c] * invN;
    float var = stats[64 + c] * invN - mean * mean;
    float sc = rsqrtf(var + 1e-5f) * gam[c];
    float v = (y[idx] - mean) * sc + bet[c];
    v = fmaxf(v, 0.f);
    if (res) v += res[idx];
    xout[idx] = v;
}

// ---------------- attention gate: gate = relu(x3@gw1+gb1)@gw2 + gb2 ----------------
__global__ void gate_kernel(const float* __restrict__ x3, const float* __restrict__ gw1,
                            const float* __restrict__ gb1, const float* __restrict__ gw2,
                            const float* __restrict__ gb2, float* __restrict__ gate) {
    __shared__ float w1s[2048];
    __shared__ float b1s[32];
    __shared__ float w2s[32];
    __shared__ float b2s;
    int t = threadIdx.x;
    for (int i = t; i < 2048; i += 256) w1s[i] = gw1[i];
    if (t < 32) { b1s[t] = gb1[t]; w2s[t] = gw2[t]; }
    if (t == 0) b2s = gb2[0];
    __syncthreads();
    int n = blockIdx.x * 256 + t;
    float hacc[32];
#pragma unroll
    for (int j = 0; j < 32; j++) hacc[j] = b1s[j];
    const float* xr = x3 + (size_t)n * 64;
    for (int i = 0; i < 64; i++) {
        float xv = xr[i];
#pragma unroll
        for (int j = 0; j < 32; j++) hacc[j] += xv * w1s[i * 32 + j];
    }
    float gv = b2s;
#pragma unroll
    for (int j = 0; j < 32; j++) gv += fmaxf(hacc[j], 0.f) * w2s[j];
    gate[n] = gv;
}

// ---------------- per-group softmax-weighted pool ----------------
__global__ void attn_pool_kernel(const float* __restrict__ x3, const float* __restrict__ gate,
                                 const int* __restrict__ batch, float* __restrict__ p) {
    int g = blockIdx.x;
    int t = threadIdx.x;
    int lo = 0, hi = NN;
    while (lo < hi) { int mid = (lo + hi) >> 1; if (batch[mid] < g) lo = mid + 1; else hi = mid; }
    int s = lo;
    hi = NN;
    while (lo < hi) { int mid = (lo + hi) >> 1; if (batch[mid] < g + 1) lo = mid + 1; else hi = mid; }
    int e = lo;

    __shared__ float red[4];
    __shared__ float sM, sZ;
    float m = -1e30f;
    for (int n = s + t; n < e; n += 256) m = fmaxf(m, gate[n]);
#pragma unroll
    for (int off = 1; off < 64; off <<= 1) m = fmaxf(m, __shfl_xor(m, off));
    if ((t & 63) == 0) red[t >> 6] = m;
    __syncthreads();
    if (t == 0) sM = fmaxf(fmaxf(red[0], red[1]), fmaxf(red[2], red[3]));
    __syncthreads();
    float z = 0.f;
    for (int n = s + t; n < e; n += 256) z += __expf(gate[n] - sM);
#pragma unroll
    for (int off = 1; off < 64; off <<= 1) z += __shfl_xor(z, off);
    if ((t & 63) == 0) red[t >> 6] = z;
    __syncthreads();
    if (t == 0) sZ = red[0] + red[1] + red[2] + red[3];
    __syncthreads();
    int w = t >> 6, c = t & 63;
    float acc = 0.f;
    for (int n = s + w; n < e; n += 4) acc += __expf(gate[n] - sM) * x3[(size_t)n * 64 + c];
    __shared__ float pa[4][64];
    pa[w][c] = acc;
    __syncthreads();
    if (t < 64) {
        float v = pa[0][t] + pa[1][t] + pa[2][t] + pa[3][t];
        p[g * 64 + t] = (sZ > 0.f) ? v / sZ : 0.f;
    }
}

// ---------------- final MLP head (single block, fully LDS-staged) ----------------
__launch_bounds__(1024)
__global__ void final_kernel(const float* __restrict__ p,
                             const float* __restrict__ fc1w, const float* __restrict__ fc1b,
                             const float* __restrict__ bn1g, const float* __restrict__ bn1b,
                             const float* __restrict__ fc2w, const float* __restrict__ fc2b,
                             const float* __restrict__ bn2g, const float* __restrict__ bn2b,
                             const float* __restrict__ fc3w, const float* __restrict__ fc3b,
                             float* __restrict__ out) {
    __shared__ float sp[4096];    // p, later reused as fc2 output
    __shared__ float w1s[8192];   // fc1w 64x128
    __shared__ float w2s[8192];   // fc2w 128x64
    __shared__ float t1[8192];    // hidden 64x128
    __shared__ float sA[128], sB[128];
    int t = threadIdx.x;
    for (int i = t; i < 4096; i += 1024) sp[i] = p[i];
    for (int i = t; i < 8192; i += 1024) w1s[i] = fc1w[i];
    for (int i = t; i < 8192; i += 1024) w2s[i] = fc2w[i];
    __syncthreads();
    for (int idx = t; idx < 8192; idx += 1024) {
        int r = idx >> 7, c = idx & 127;
        float s = fc1b[c];
#pragma unroll
        for (int i = 0; i < 64; i++) s += sp[r * 64 + i] * w1s[i * 128 + c];
        t1[idx] = s;
    }
    __syncthreads();
    if (t < 128) {
        float su = 0.f, sq = 0.f;
        for (int r = 0; r < 64; r++) { float v = t1[r * 128 + t]; su += v; sq += v * v; }
        float mean = su * (1.f / 64.f);
        float var = sq * (1.f / 64.f) - mean * mean;
        float sc = rsqrtf(var + 1e-5f) * bn1g[t];
        sA[t] = sc; sB[t] = bn1b[t] - mean * sc;
    }
    __syncthreads();
    for (int idx = t; idx < 8192; idx += 1024) {
        int c = idx & 127;
        t1[idx] = fmaxf(t1[idx] * sA[c] + sB[c], 0.f);
    }
    __syncthreads();
    for (int idx = t; idx < 4096; idx += 1024) {
        int r = idx >> 6, c = idx & 63;
        float s = fc2b[c];
#pragma unroll
        for (int i = 0; i < 128; i++) s += t1[r * 128 + i] * w2s[i * 64 + c];
        sp[idx] = s;
    }
    __syncthreads();
    if (t < 64) {
        float su = 0.f, sq = 0.f;
        for (int r = 0; r < 64; r++) { float v = sp[r * 64 + t]; su += v; sq += v * v; }
        float mean = su * (1.f / 64.f);
        float var = sq * (1.f / 64.f) - mean * mean;
        float sc = rsqrtf(var + 1e-5f) * bn2g[t];
        sA[t] = sc; sB[t] = bn2b[t] - mean * sc;
    }
    __syncthreads();
    if (t < 64) {
        float s = fc3b[0];
        for (int ii = 0; ii < 64; ++ii) {
            int i = (ii + t) & 63;  // rotate to avoid LDS bank conflict
            float v = fmaxf(sp[t * 64 + i] * sA[i] + sB[i], 0.f);
            s += v * fc3w[i];
        }
        out[t] = s;
    }
}

extern "C" void kernel_launch(void* const* d_in, const int* in_sizes, int n_in,
                              void* d_out, int out_size, void* d_ws, size_t ws_size,
                              hipStream_t stream) {
    const float* x     = (const float*)d_in[0];
    const int*   eidx  = (const int*)d_in[1];
    const float* eattr = (const float*)d_in[2];
    const int*   batch = (const int*)d_in[3];
    const float* e1w1 = (const float*)d_in[4];  const float* e1b1 = (const float*)d_in[5];
    const float* e1w2 = (const float*)d_in[6];  const float* e1b2 = (const float*)d_in[7];
    const float* r1w  = (const float*)d_in[8];  const float* r1b  = (const float*)d_in[9];
    const float* bn1g = (const float*)d_in[10]; const float* bn1b = (const float*)d_in[11];
    const float* e2w1 = (const float*)d_in[12]; const float* e2b1 = (const float*)d_in[13];
    const float* e2w2 = (const float*)d_in[14]; const float* e2b2 = (const float*)d_in[15];
    const float* r2w  = (const float*)d_in[16]; const float* r2b  = (const float*)d_in[17];
    const float* bn2g = (const float*)d_in[18]; const float* bn2b = (const float*)d_in[19];
    const float* e3w1 = (const float*)d_in[20]; const float* e3b1 = (const float*)d_in[21];
    const float* e3w2 = (const float*)d_in[22]; const float* e3b2 = (const float*)d_in[23];
    const float* r3w  = (const float*)d_in[24]; const float* r3b  = (const float*)d_in[25];
    const float* bn3g = (const float*)d_in[26]; const float* bn3b = (const float*)d_in[27];
    const float* gw1  = (const float*)d_in[28]; const float* gb1  = (const float*)d_in[29];
    const float* gw2  = (const float*)d_in[30]; const float* gb2  = (const float*)d_in[31];
    const float* fc1w = (const float*)d_in[32]; const float* fc1b = (const float*)d_in[33];
    const float* fbn1g= (const float*)d_in[34]; const float* fbn1b= (const float*)d_in[35];
    const float* fc2w = (const float*)d_in[36]; const float* fc2b = (const float*)d_in[37];
    const float* fbn2g= (const float*)d_in[38]; const float* fbn2b= (const float*)d_in[39];
    const float* fc3w = (const float*)d_in[40]; const float* fc3b = (const float*)d_in[41];
    float* out = (float*)d_out;

    const int* src = eidx;
    const int* dst = eidx + EE;

    char* ws = (char*)d_ws;
    size_t off = 0;
    auto take = [&](size_t n) { void* p = ws + off; off = (off + n + 255) & ~(size_t)255; return p; };
    ushort_t* Bt1 = (ushort_t*)take(64 * 2080 * 2);
    ushort_t* Bt2 = (ushort_t*)take(64 * 4160 * 2);
    ushort_t* Bt3 = (ushort_t*)take(64 * 4160 * 2);
    float* msg  = (float*)take((size_t)EE * 64 * 4);
    float* ybuf = (float*)take((size_t)NN * 64 * 4);
    float* x1   = (float*)take((size_t)NN * 64 * 4);
    float* x2   = (float*)take((size_t)NN * 64 * 4);
    float* x3   = (float*)take((size_t)NN * 64 * 4);
    float* gate = (float*)take((size_t)NN * 4);
    float* pbuf = (float*)take(64 * 64 * 4);
    float* stats = (float*)take(384 * 4);
    int* cnt  = (int*)take((size_t)NN * 4);
    int* fill = (int*)take((size_t)NN * 4);
    int* rowp = (int*)take((size_t)(NN + 1) * 4);
    int* perm = (int*)take((size_t)EE * 4);

    zero_kernel<<<32, 256, 0, stream>>>(cnt, fill, stats);
    btbuild_kernel<32><<<520, 256, 0, stream>>>(e1w2, e1b2, Bt1);
    btbuild_kernel<64><<<1040, 256, 0, stream>>>(e2w2, e2b2, Bt2);
    btbuild_kernel<64><<<1040, 256, 0, stream>>>(e3w2, e3b2, Bt3);
    hist_kernel<<<160, 256, 0, stream>>>(dst, cnt);
    scan_kernel<<<1, 1024, 0, stream>>>(cnt, rowp);
    scatter_kernel<<<160, 256, 0, stream>>>(dst, rowp, fill, perm);

    // layer 1 (IC = 32)
    conv_msg_kernel<32><<<640, 256, 0, stream>>>(eattr, e1w1, e1b1, x, src, perm, Bt1, msg);
    aggregate_kernel<<<512, 256, 0, stream>>>(msg, rowp, x, 32, r1w, r1b, ybuf, stats);
    bn_apply_kernel<<<2048, 256, 0, stream>>>(ybuf, stats, bn1g, bn1b, nullptr, x1);

    // layer 2 (IC = 64)
    conv_msg_kernel<64><<<640, 256, 0, stream>>>(eattr, e2w1, e2b1, x1, src, perm, Bt2, msg);
    aggregate_kernel<<<512, 256, 0, stream>>>(msg, rowp, x1, 64, r2w, r2b, ybuf, stats + 128);
    bn_apply_kernel<<<2048, 256, 0, stream>>>(ybuf, stats + 128, bn2g, bn2b, x1, x2);

    // layer 3 (IC = 64)
    conv_msg_kernel<64><<<640, 256, 0, stream>>>(eattr, e3w1, e3b1, x2, src, perm, Bt3, msg);
    aggregate_kernel<<<512, 256, 0, stream>>>(msg, rowp, x2, 64, r3w, r3b, ybuf, stats + 256);
    bn_apply_kernel<<<2048, 256, 0, stream>>>(ybuf, stats + 256, bn3g, bn3b, x2, x3);

    gate_kernel<<<32, 256, 0, stream>>>(x3, gw1, gb1, gw2, gb2, gate);
    attn_pool_kernel<<<64, 256, 0, stream>>>(x3, gate, batch, pbuf);
    final_kernel<<<1, 1024, 0, stream>>>(pbuf, fc1w, fc1b, fbn1g, fbn1b,
                                         fc2w, fc2b, fbn2g, fbn2b, fc3w, fc3b, out);
}